// Round 1
// baseline (2499.300 us; speedup 1.0000x reference)
//
#include <hip/hip_runtime.h>

#define NNODES 8000
#define NEDGES 40000
#define ETOT   (NEDGES + NNODES)   // 48000 (with self loops)
#define DIN    1024
#define NH     3
#define CH     1024
#define HC     (NH * CH)           // 3072
#define NCLS   460
#define NCLS_P 512                 // padded logits leading dim
#define NEG    0.2f

// ---------- helpers: order-preserving float<->uint encode for atomicMax ----------
__device__ __forceinline__ unsigned encodeF(float f) {
    unsigned u = __float_as_uint(f);
    return (u & 0x80000000u) ? ~u : (u | 0x80000000u);
}
__device__ __forceinline__ float decodeF(unsigned u) {
    return (u & 0x80000000u) ? __uint_as_float(u & 0x7FFFFFFFu) : __uint_as_float(~u);
}

// ---------- tiled fp32 GEMM: C[M,Npad] = (A[M,K] (+abias per-k)) @ B[K,realN] (+cbias per-n)
// BM=BN=64, BK=16, 256 threads, 4x4 micro-tile per thread.
__global__ __launch_bounds__(256)
void gemm_tiled(const float* __restrict__ A, const float* __restrict__ B,
                const float* __restrict__ abias, const float* __restrict__ cbias,
                float* __restrict__ C, int K, int Npad, int realN)
{
    __shared__ float As[16][68];   // [k][m], padded: rows start 272B apart (16B-aligned)
    __shared__ float Bs[16][68];   // [k][n]

    const int t  = threadIdx.x;
    const int tx = t & 15;
    const int ty = t >> 4;
    const int m0 = blockIdx.y * 64;
    const int n0 = blockIdx.x * 64;

    float acc[4][4] = {};

    for (int k0 = 0; k0 < K; k0 += 16) {
        // A tile: 64 rows x 16 k  (1024 elems, 4/thread)
        #pragma unroll
        for (int i = 0; i < 4; ++i) {
            int idx = t + i * 256;
            int row = idx >> 4;
            int col = idx & 15;
            float av = A[(size_t)(m0 + row) * K + (k0 + col)];
            if (abias) av += abias[k0 + col];
            As[col][row] = av;
        }
        // B tile: 16 k x 64 n (guard n for realN < Npad)
        #pragma unroll
        for (int i = 0; i < 4; ++i) {
            int idx = t + i * 256;
            int row = idx >> 6;
            int col = idx & 63;
            int n = n0 + col;
            Bs[row][col] = (n < realN) ? B[(size_t)(k0 + row) * realN + n] : 0.f;
        }
        __syncthreads();
        #pragma unroll
        for (int kk = 0; kk < 16; ++kk) {
            float4 av = *(const float4*)&As[kk][ty << 2];
            float4 bv = *(const float4*)&Bs[kk][tx << 2];
            float a_[4] = {av.x, av.y, av.z, av.w};
            float b_[4] = {bv.x, bv.y, bv.z, bv.w};
            #pragma unroll
            for (int i = 0; i < 4; ++i)
                #pragma unroll
                for (int j = 0; j < 4; ++j)
                    acc[i][j] = fmaf(a_[i], b_[j], acc[i][j]);
        }
        __syncthreads();
    }

    #pragma unroll
    for (int i = 0; i < 4; ++i) {
        size_t m = (size_t)(m0 + (ty << 2) + i);
        int n = n0 + (tx << 2);
        float4 o;
        o.x = acc[i][0] + ((n + 0) < realN ? cbias[n + 0] : 0.f);
        o.y = acc[i][1] + ((n + 1) < realN ? cbias[n + 1] : 0.f);
        o.z = acc[i][2] + ((n + 2) < realN ? cbias[n + 2] : 0.f);
        o.w = acc[i][3] + ((n + 3) < realN ? cbias[n + 3] : 0.f);
        *(float4*)&C[m * Npad + n] = o;
    }
}

// ---------- per-edge attention scores e[edge,h] = att[h,:] . lrelu(xl[src,h,:]+xr[dst,h,:])
__global__ __launch_bounds__(256)
void edge_scores(const float* __restrict__ xl, const float* __restrict__ xr,
                 const int* __restrict__ ei, const float* __restrict__ att,
                 float* __restrict__ sc, unsigned* __restrict__ mEnc)
{
    const int e = blockIdx.x;
    int src, dst;
    if (e < NEDGES) { src = ei[2 * e]; dst = ei[2 * e + 1]; }
    else            { src = dst = e - NEDGES; }
    const int t = threadIdx.x;
    __shared__ float red[4];

    for (int h = 0; h < NH; ++h) {
        float4 vl = ((const float4*)(xl + (size_t)src * HC + h * CH))[t];
        float4 vr = ((const float4*)(xr + (size_t)dst * HC + h * CH))[t];
        float4 va = ((const float4*)(att + h * CH))[t];
        float s, z;
        z = vl.x + vr.x; s  = va.x * (z > 0.f ? z : NEG * z);
        z = vl.y + vr.y; s += va.y * (z > 0.f ? z : NEG * z);
        z = vl.z + vr.z; s += va.z * (z > 0.f ? z : NEG * z);
        z = vl.w + vr.w; s += va.w * (z > 0.f ? z : NEG * z);
        #pragma unroll
        for (int off = 32; off > 0; off >>= 1) s += __shfl_down(s, off);
        if ((t & 63) == 0) red[t >> 6] = s;
        __syncthreads();
        if (t == 0) {
            float tot = red[0] + red[1] + red[2] + red[3];
            sc[(size_t)e * NH + h] = tot;
            atomicMax(&mEnc[dst * NH + h], encodeF(tot));
        }
        __syncthreads();
    }
}

// ---------- a = exp(e - m[dst]); denom[dst] += a
__global__ __launch_bounds__(256)
void edge_exp(const int* __restrict__ ei, const unsigned* __restrict__ mEnc,
              float* __restrict__ sc, float* __restrict__ den)
{
    int g = blockIdx.x * 256 + threadIdx.x;
    if (g >= ETOT * NH) return;
    int e = g / NH;
    int h = g - e * NH;
    int dst = (e < NEDGES) ? ei[2 * e + 1] : (e - NEDGES);
    float m = decodeF(mEnc[dst * NH + h]);
    float a = expf(sc[g] - m);
    sc[g] = a;
    atomicAdd(&den[dst * NH + h], a);
}

// ---------- out2[dst,c] += sum_h alpha[e,h]/3 * xl[src,h,c]  (head-mean folded in)
__global__ __launch_bounds__(256)
void scatter_out(const float* __restrict__ xl, const int* __restrict__ ei,
                 const float* __restrict__ sc, const float* __restrict__ den,
                 float* __restrict__ out2)
{
    const int e = blockIdx.x;
    int src, dst;
    if (e < NEDGES) { src = ei[2 * e]; dst = ei[2 * e + 1]; }
    else            { src = dst = e - NEDGES; }
    const float c0 = sc[(size_t)e * NH + 0] / (den[dst * NH + 0] + 1e-16f) * (1.f / 3.f);
    const float c1 = sc[(size_t)e * NH + 1] / (den[dst * NH + 1] + 1e-16f) * (1.f / 3.f);
    const float c2 = sc[(size_t)e * NH + 2] / (den[dst * NH + 2] + 1e-16f) * (1.f / 3.f);
    const int t = threadIdx.x;
    const float4* p = (const float4*)(xl + (size_t)src * HC);
    float4 v0 = p[t], v1 = p[t + 256], v2 = p[t + 512];
    float4 w;
    w.x = c0 * v0.x + c1 * v1.x + c2 * v2.x;
    w.y = c0 * v0.y + c1 * v1.y + c2 * v2.y;
    w.z = c0 * v0.z + c1 * v1.z + c2 * v2.z;
    w.w = c0 * v0.w + c1 * v1.w + c2 * v2.w;
    float* o = out2 + (size_t)dst * CH + t * 4;
    atomicAdd(o + 0, w.x);
    atomicAdd(o + 1, w.y);
    atomicAdd(o + 2, w.z);
    atomicAdd(o + 3, w.w);
}

// ---------- row softmax over 460 classes (1 wave / row)
__global__ __launch_bounds__(64)
void row_softmax(const float* __restrict__ logits, float* __restrict__ out)
{
    const int r = blockIdx.x;
    const int lane = threadIdx.x;
    const float* row = logits + (size_t)r * NCLS_P;
    float v[8];
    float mx = -3.4e38f;
    #pragma unroll
    for (int i = 0; i < 8; ++i) {
        int c = lane + i * 64;
        v[i] = (c < NCLS) ? row[c] : -3.4e38f;
        mx = fmaxf(mx, v[i]);
    }
    #pragma unroll
    for (int off = 32; off > 0; off >>= 1) mx = fmaxf(mx, __shfl_xor(mx, off));
    float s = 0.f;
    #pragma unroll
    for (int i = 0; i < 8; ++i) {
        int c = lane + i * 64;
        float ev = (c < NCLS) ? expf(v[i] - mx) : 0.f;
        v[i] = ev;
        s += ev;
    }
    #pragma unroll
    for (int off = 32; off > 0; off >>= 1) s += __shfl_xor(s, off);
    float inv = 1.f / s;
    #pragma unroll
    for (int i = 0; i < 8; ++i) {
        int c = lane + i * 64;
        if (c < NCLS) out[(size_t)r * NCLS + c] = v[i] * inv;
    }
}

extern "C" void kernel_launch(void* const* d_in, const int* in_sizes, int n_in,
                              void* d_out, int out_size, void* d_ws, size_t ws_size,
                              hipStream_t stream)
{
    (void)in_sizes; (void)n_in; (void)out_size; (void)ws_size;

    const float* x    = (const float*)d_in[0];
    const int*   ei   = (const int*)  d_in[1];
    const float* Wl   = (const float*)d_in[2];
    const float* bl   = (const float*)d_in[3];
    const float* Wr   = (const float*)d_in[4];
    const float* br   = (const float*)d_in[5];
    const float* att  = (const float*)d_in[6];
    const float* bias = (const float*)d_in[7];
    const float* Wf   = (const float*)d_in[8];
    const float* bf   = (const float*)d_in[9];
    // d_in[10] (exps), d_in[11] (exps_c) unused by the reference output.

    float* ws = (float*)d_ws;
    float*    xl     = ws;                                   // [N, H*C]
    float*    xr     = xl + (size_t)NNODES * HC;             // [N, H*C]
    float*    sc     = xr + (size_t)NNODES * HC;             // [ETOT, H] scores -> exp(a)
    unsigned* mEnc   = (unsigned*)(sc + (size_t)ETOT * NH);  // [N, H] encoded max
    float*    den    = (float*)(mEnc + NNODES * NH);         // [N, H]
    float*    out2   = den + NNODES * NH;                    // [N, C] head-mean accumulator
    float*    logits = out2 + (size_t)NNODES * CH;           // [N, NCLS_P]

    // zero the accumulators (mEnc, den, out2 are contiguous)
    hipMemsetAsync(mEnc, 0,
                   (size_t)(NNODES * NH * 2 + (size_t)NNODES * CH) * sizeof(float),
                   stream);

    dim3 g1(HC / 64, NNODES / 64);       // 48 x 125
    gemm_tiled<<<g1, 256, 0, stream>>>(x, Wl, nullptr, bl, xl, DIN, HC, HC);
    gemm_tiled<<<g1, 256, 0, stream>>>(x, Wr, nullptr, br, xr, DIN, HC, HC);

    edge_scores<<<ETOT, 256, 0, stream>>>(xl, xr, ei, att, sc, mEnc);
    edge_exp<<<(ETOT * NH + 255) / 256, 256, 0, stream>>>(ei, mEnc, sc, den);
    scatter_out<<<ETOT, 256, 0, stream>>>(xl, ei, sc, den, out2);

    dim3 g2(NCLS_P / 64, NNODES / 64);   // 8 x 125
    gemm_tiled<<<g2, 256, 0, stream>>>(out2, Wf, bias, bf, logits, CH, NCLS_P, NCLS);

    row_softmax<<<NNODES, 64, 0, stream>>>(logits, (float*)d_out);
}

// Round 2
// 1023.951 us; speedup vs baseline: 2.4408x; 2.4408x over previous
//
#include <hip/hip_runtime.h>

#define NNODES 8000
#define MPAD   8064          // 63 * 128
#define NEDGES 40000
#define ETOT   (NEDGES + NNODES)   // 48000 with self loops
#define DIN    1024
#define NH     3
#define CH     1024
#define HC     (NH * CH)           // 3072
#define NTOT   (2 * HC)            // 6144 fused xl||xr
#define NCLS   460
#define NCLS_P 512
#define NEG    0.2f

typedef _Float16 h8 __attribute__((ext_vector_type(8)));
typedef _Float16 h4v __attribute__((ext_vector_type(4)));
typedef float    f4 __attribute__((ext_vector_type(4)));

// ---------- order-preserving float<->uint encode for atomicMax ----------
__device__ __forceinline__ unsigned encodeF(float f) {
    unsigned u = __float_as_uint(f);
    return (u & 0x80000000u) ? ~u : (u | 0x80000000u);
}
__device__ __forceinline__ float decodeF(unsigned u) {
    return (u & 0x80000000u) ? __uint_as_float(u & 0x7FFFFFFFu) : __uint_as_float(~u);
}

// ---------- fp32 -> fp16 convert with row padding and optional per-col add ----------
__global__ __launch_bounds__(256)
void fp16_pad_convert(const float* __restrict__ in, _Float16* __restrict__ out,
                      const float* __restrict__ addv, int rows_in, int rows_out, int cols)
{
    size_t i4 = (size_t)blockIdx.x * 256 + threadIdx.x;
    size_t tot = ((size_t)rows_out * cols) >> 2;
    if (i4 >= tot) return;
    size_t e = i4 << 2;
    int row = (int)(e / cols);
    int c   = (int)(e - (size_t)row * cols);
    float vx = 0.f, vy = 0.f, vz = 0.f, vw = 0.f;
    if (row < rows_in) {
        const float* p = in + (size_t)row * cols + c;
        float4 v = *(const float4*)p;
        vx = v.x; vy = v.y; vz = v.z; vw = v.w;
    }
    if (addv && row < rows_in) {
        vx += addv[c]; vy += addv[c + 1]; vz += addv[c + 2]; vw += addv[c + 3];
    }
    h4v o = { (_Float16)vx, (_Float16)vy, (_Float16)vz, (_Float16)vw };
    *(h4v*)(out + e) = o;
}

// ---------- W[K][Ncols] fp32 -> Wt[rowOff+n][K] fp16 (zero for n >= Ncols) ----------
__global__ __launch_bounds__(256)
void transpose_to_fp16(const float* __restrict__ W, _Float16* __restrict__ Wt,
                       int K, int Ncols, int rowOff)
{
    __shared__ float tile[32][33];
    int n0 = blockIdx.x * 32, k0 = blockIdx.y * 32;
    int tx = threadIdx.x, ty = threadIdx.y;   // block (32,8)
    #pragma unroll
    for (int i = 0; i < 4; ++i) {
        int k = k0 + ty + i * 8;
        int n = n0 + tx;
        tile[ty + i * 8][tx] = (n < Ncols) ? W[(size_t)k * Ncols + n] : 0.f;
    }
    __syncthreads();
    #pragma unroll
    for (int i = 0; i < 4; ++i) {
        int n = n0 + ty + i * 8;
        int k = k0 + tx;
        Wt[(size_t)(rowOff + n) * K + k] = (_Float16)tile[tx][ty + i * 8];
    }
}

// ---------- pack biases: b1[6144] = bl||br ; b2[512] = bf padded 0 ----------
__global__ __launch_bounds__(256)
void bias_pack(const float* __restrict__ bl, const float* __restrict__ br,
               const float* __restrict__ bf, float* __restrict__ b1, float* __restrict__ b2)
{
    int i = blockIdx.x * 256 + threadIdx.x;
    if (i < HC) { b1[i] = bl[i]; b1[HC + i] = br[i]; }
    if (i < NCLS_P) b2[i] = (i < NCLS) ? bf[i] : 0.f;
}

// ---------- fp16 MFMA GEMM: C[Mpad][N] = A[Mpad][K] * Bt[N][K]^T + biasN ----------
// 128x128 tile, BK=32, 4 waves (2x2, 64x64 each), XOR-swizzled LDS, XCD-swizzled grid.
__global__ __launch_bounds__(256, 3)
void gemm_f16(const _Float16* __restrict__ A, const _Float16* __restrict__ Bt,
              const float* __restrict__ biasN,
              float* __restrict__ C32, _Float16* __restrict__ C16,
              int N, int K)
{
    __shared__ __align__(16) _Float16 sA[128 * 32];
    __shared__ __align__(16) _Float16 sB[128 * 32];

    // bijective XCD swizzle (m204)
    int nwg = gridDim.x;
    int orig = blockIdx.x;
    int q = nwg >> 3, r = nwg & 7;
    int xcd = orig & 7, idx = orig >> 3;
    int wg = (xcd < r ? xcd * (q + 1) : r * (q + 1) + (xcd - r) * q) + idx;
    int nbx = N >> 7;
    int bm = wg / nbx, bn = wg - bm * nbx;
    int m0 = bm << 7, n0 = bn << 7;

    const int t = threadIdx.x;
    const int lane = t & 63, w = t >> 6;
    const int wr = (w >> 1) << 6, wc = (w & 1) << 6;

    f4 acc[4][4];
    f4 zero = { 0.f, 0.f, 0.f, 0.f };
    #pragma unroll
    for (int i = 0; i < 4; ++i)
        #pragma unroll
        for (int j = 0; j < 4; ++j) acc[i][j] = zero;

    // staging: thread t handles 16B units (row r0, kslot ks0) and (row r0+64, ks0)
    const int r0 = t >> 2, ks0 = t & 3;
    const int r1 = r0 + 64;
    const int wA0 = r0 * 32 + ((ks0 ^ ((r0 >> 1) & 3)) << 3);  // swizzled LDS elem offset
    const int wA1 = r1 * 32 + ((ks0 ^ ((r1 >> 1) & 3)) << 3);
    const _Float16* gA0 = A  + (size_t)(m0 + r0) * K + ks0 * 8;
    const _Float16* gA1 = A  + (size_t)(m0 + r1) * K + ks0 * 8;
    const _Float16* gB0 = Bt + (size_t)(n0 + r0) * K + ks0 * 8;
    const _Float16* gB1 = Bt + (size_t)(n0 + r1) * K + ks0 * 8;

    uint4 stA0 = *(const uint4*)gA0;
    uint4 stA1 = *(const uint4*)gA1;
    uint4 stB0 = *(const uint4*)gB0;
    uint4 stB1 = *(const uint4*)gB1;

    const int nk = K >> 5;
    for (int s = 0; s < nk; ++s) {
        __syncthreads();
        *(uint4*)&sA[wA0] = stA0;
        *(uint4*)&sA[wA1] = stA1;
        *(uint4*)&sB[wA0] = stB0;
        *(uint4*)&sB[wA1] = stB1;
        __syncthreads();
        if (s + 1 < nk) {
            int koff = (s + 1) << 5;
            stA0 = *(const uint4*)(gA0 + koff);
            stA1 = *(const uint4*)(gA1 + koff);
            stB0 = *(const uint4*)(gB0 + koff);
            stB1 = *(const uint4*)(gB1 + koff);
        }
        const int ks = lane >> 4;
        h8 bh[4];
        #pragma unroll
        for (int nj = 0; nj < 4; ++nj) {
            int rn = wc + nj * 16 + (lane & 15);
            bh[nj] = *(const h8*)&sB[rn * 32 + ((ks ^ ((rn >> 1) & 3)) << 3)];
        }
        #pragma unroll
        for (int mi = 0; mi < 4; ++mi) {
            int rm = wr + mi * 16 + (lane & 15);
            h8 ah = *(const h8*)&sA[rm * 32 + ((ks ^ ((rm >> 1) & 3)) << 3)];
            #pragma unroll
            for (int nj = 0; nj < 4; ++nj)
                acc[mi][nj] = __builtin_amdgcn_mfma_f32_16x16x32_f16(ah, bh[nj], acc[mi][nj], 0, 0, 0);
        }
    }

    // epilogue: C/D layout col=lane&15, row=(lane>>4)*4+reg (m89-verified)
    #pragma unroll
    for (int mi = 0; mi < 4; ++mi) {
        #pragma unroll
        for (int nj = 0; nj < 4; ++nj) {
            int col  = n0 + wc + nj * 16 + (lane & 15);
            int rowb = m0 + wr + mi * 16 + ((lane >> 4) << 2);
            float b = biasN[col];
            #pragma unroll
            for (int rg = 0; rg < 4; ++rg) {
                float v = acc[mi][nj][rg] + b;
                size_t off = (size_t)(rowb + rg) * N + col;
                if (C32) C32[off] = v;
                else     C16[off] = (_Float16)v;
            }
        }
    }
}

// ---------- scores: one wave per (edge, head) ----------
__global__ __launch_bounds__(256)
void edge_scores(const _Float16* __restrict__ xlr, const int* __restrict__ ei,
                 const float* __restrict__ att, float* __restrict__ sc,
                 unsigned* __restrict__ mEnc)
{
    int gw = (blockIdx.x << 2) + (threadIdx.x >> 6);
    if (gw >= ETOT * NH) return;
    int e = gw / 3, h = gw - e * 3;
    int lane = threadIdx.x & 63;
    int src, dst;
    if (e < NEDGES) { src = ei[2 * e]; dst = ei[2 * e + 1]; }
    else            { src = dst = e - NEDGES; }
    const _Float16* pl = xlr + (size_t)src * NTOT + h * CH + lane * 16;
    const _Float16* pr = xlr + (size_t)dst * NTOT + HC + h * CH + lane * 16;
    const float*    pa = att + h * CH + lane * 16;
    float s = 0.f;
    #pragma unroll
    for (int j = 0; j < 16; j += 8) {
        h8 vl = *(const h8*)(pl + j);
        h8 vr = *(const h8*)(pr + j);
        float4 a0 = *(const float4*)(pa + j);
        float4 a1 = *(const float4*)(pa + j + 4);
        float av[8] = { a0.x, a0.y, a0.z, a0.w, a1.x, a1.y, a1.z, a1.w };
        #pragma unroll
        for (int k = 0; k < 8; ++k) {
            float z = (float)vl[k] + (float)vr[k];
            z = z > 0.f ? z : NEG * z;
            s = fmaf(av[k], z, s);
        }
    }
    #pragma unroll
    for (int off = 32; off > 0; off >>= 1) s += __shfl_down(s, off);
    if (lane == 0) {
        sc[gw] = s;
        atomicMax(&mEnc[dst * NH + h], encodeF(s));
    }
}

// ---------- a = exp(e - m[dst]); denom[dst] += a ----------
__global__ __launch_bounds__(256)
void edge_exp(const int* __restrict__ ei, const unsigned* __restrict__ mEnc,
              float* __restrict__ sc, float* __restrict__ den)
{
    int g = blockIdx.x * 256 + threadIdx.x;
    if (g >= ETOT * NH) return;
    int e = g / 3, h = g - e * 3;
    int dst = (e < NEDGES) ? ei[2 * e + 1] : (e - NEDGES);
    float m = decodeF(mEnc[dst * NH + h]);
    float a = expf(sc[g] - m);
    sc[g] = a;
    atomicAdd(&den[dst * NH + h], a);
}

// ---------- out2[dst] += sum_h alpha/3 * xl[src,h,:] ----------
__global__ __launch_bounds__(256)
void scatter_out(const _Float16* __restrict__ xlr, const int* __restrict__ ei,
                 const float* __restrict__ sc, const float* __restrict__ den,
                 float* __restrict__ out2)
{
    const int e = blockIdx.x;
    int src, dst;
    if (e < NEDGES) { src = ei[2 * e]; dst = ei[2 * e + 1]; }
    else            { src = dst = e - NEDGES; }
    const float c0 = sc[e * NH + 0] / (den[dst * NH + 0] + 1e-16f) * (1.f / 3.f);
    const float c1 = sc[e * NH + 1] / (den[dst * NH + 1] + 1e-16f) * (1.f / 3.f);
    const float c2 = sc[e * NH + 2] / (den[dst * NH + 2] + 1e-16f) * (1.f / 3.f);
    const int t = threadIdx.x;
    const _Float16* p = xlr + (size_t)src * NTOT + 4 * t;
    h4v v0 = *(const h4v*)(p);
    h4v v1 = *(const h4v*)(p + CH);
    h4v v2 = *(const h4v*)(p + 2 * CH);
    float* o = out2 + (size_t)dst * CH + 4 * t;
    atomicAdd(o + 0, c0 * (float)v0[0] + c1 * (float)v1[0] + c2 * (float)v2[0]);
    atomicAdd(o + 1, c0 * (float)v0[1] + c1 * (float)v1[1] + c2 * (float)v2[1]);
    atomicAdd(o + 2, c0 * (float)v0[2] + c1 * (float)v1[2] + c2 * (float)v2[2]);
    atomicAdd(o + 3, c0 * (float)v0[3] + c1 * (float)v1[3] + c2 * (float)v2[3]);
}

// ---------- row softmax over 460 classes, ld 512 ----------
__global__ __launch_bounds__(64)
void row_softmax(const float* __restrict__ logits, float* __restrict__ out)
{
    const int r = blockIdx.x;
    const int lane = threadIdx.x;
    const float* row = logits + (size_t)r * NCLS_P;
    float v[8];
    float mx = -3.4e38f;
    #pragma unroll
    for (int i = 0; i < 8; ++i) {
        int c = lane + i * 64;
        v[i] = (c < NCLS) ? row[c] : -3.4e38f;
        mx = fmaxf(mx, v[i]);
    }
    #pragma unroll
    for (int off = 32; off > 0; off >>= 1) mx = fmaxf(mx, __shfl_xor(mx, off));
    float s = 0.f;
    #pragma unroll
    for (int i = 0; i < 8; ++i) {
        int c = lane + i * 64;
        float ev = (c < NCLS) ? expf(v[i] - mx) : 0.f;
        v[i] = ev;
        s += ev;
    }
    #pragma unroll
    for (int off = 32; off > 0; off >>= 1) s += __shfl_xor(s, off);
    float inv = 1.f / s;
    #pragma unroll
    for (int i = 0; i < 8; ++i) {
        int c = lane + i * 64;
        if (c < NCLS) out[(size_t)r * NCLS + c] = v[i] * inv;
    }
}

extern "C" void kernel_launch(void* const* d_in, const int* in_sizes, int n_in,
                              void* d_out, int out_size, void* d_ws, size_t ws_size,
                              hipStream_t stream)
{
    (void)in_sizes; (void)n_in; (void)out_size; (void)ws_size;

    const float* x    = (const float*)d_in[0];
    const int*   ei   = (const int*)  d_in[1];
    const float* Wl   = (const float*)d_in[2];
    const float* bl   = (const float*)d_in[3];
    const float* Wr   = (const float*)d_in[4];
    const float* br   = (const float*)d_in[5];
    const float* att  = (const float*)d_in[6];
    const float* bias = (const float*)d_in[7];
    const float* Wf   = (const float*)d_in[8];
    const float* bf   = (const float*)d_in[9];

    char* base = (char*)d_ws;
    _Float16* xh     = (_Float16*)(base);                       // [8064][1024]
    _Float16* BtW    = (_Float16*)(base + 16515072);            // [6144][1024] (Wl^T || Wr^T)
    _Float16* Wft    = (_Float16*)(base + 29097984);            // [512][1024]
    float*    biasC1 = (float*)   (base + 30146560);            // [6144]
    float*    biasC2 = (float*)   (base + 30171136);            // [512]
    float*    sc     = (float*)   (base + 30173184);            // [48000*3]
    unsigned* mEnc   = (unsigned*)(base + 30749184);            // [8000*3]
    float*    den    = (float*)   (base + 30845184);            // [8000*3]
    float*    out2   = (float*)   (base + 30941184);            // [8000][1024]
    _Float16* o2h    = (_Float16*)(base + 63709184);            // [8064][1024]
    float*    logits = (float*)   (base + 80224256);            // [8064][512]
    _Float16* xlr    = (_Float16*)(base + 96739328);            // [8064][6144]

    // zero mEnc|den|out2 (contiguous, 32,960,000 B)
    hipMemsetAsync(mEnc, 0, 32960000, stream);

    // convert x -> fp16 padded
    fp16_pad_convert<<<(MPAD * DIN / 4 + 255) / 256, 256, 0, stream>>>(
        x, xh, nullptr, NNODES, MPAD, DIN);

    // transpose weights to [N][K] fp16
    transpose_to_fp16<<<dim3(HC / 32, DIN / 32), dim3(32, 8), 0, stream>>>(Wl, BtW, DIN, HC, 0);
    transpose_to_fp16<<<dim3(HC / 32, DIN / 32), dim3(32, 8), 0, stream>>>(Wr, BtW, DIN, HC, HC);
    transpose_to_fp16<<<dim3(NCLS_P / 32, DIN / 32), dim3(32, 8), 0, stream>>>(Wf, Wft, DIN, NCLS, 0);

    bias_pack<<<(HC + 255) / 256, 256, 0, stream>>>(bl, br, bf, biasC1, biasC2);

    // GEMM1 fused: xlr[8064][6144] fp16
    gemm_f16<<<(NTOT / 128) * (MPAD / 128), 256, 0, stream>>>(
        xh, BtW, biasC1, nullptr, xlr, NTOT, DIN);

    // edge path
    edge_scores<<<(ETOT * NH + 3) / 4, 256, 0, stream>>>(xlr, ei, att, sc, mEnc);
    edge_exp<<<(ETOT * NH + 255) / 256, 256, 0, stream>>>(ei, mEnc, sc, den);
    scatter_out<<<ETOT, 256, 0, stream>>>(xlr, ei, sc, den, out2);

    // out2 + bias -> fp16 padded
    fp16_pad_convert<<<(MPAD * CH / 4 + 255) / 256, 256, 0, stream>>>(
        out2, o2h, bias, NNODES, MPAD, CH);

    // GEMM2: logits[8064][512] fp32
    gemm_f16<<<(NCLS_P / 128) * (MPAD / 128), 256, 0, stream>>>(
        o2h, Wft, biasC2, logits, nullptr, NCLS_P, DIN);

    row_softmax<<<NNODES, 64, 0, stream>>>(logits, (float*)d_out);
}

// Round 4
// 445.498 us; speedup vs baseline: 5.6101x; 2.2984x over previous
//
#include <hip/hip_runtime.h>

#define NNODES 8000
#define MPAD   8064          // 63 * 128
#define NEDGES 40000
#define ETOT   (NEDGES + NNODES)   // 48000 with self loops
#define DIN    1024
#define NH     3
#define CH     1024
#define HC     (NH * CH)           // 3072
#define NTOT   (2 * HC)            // 6144 fused xl||xr
#define NCLS   460
#define NCLS_P 512
#define NEG    0.2f

typedef _Float16 h8 __attribute__((ext_vector_type(8)));
typedef _Float16 h4v __attribute__((ext_vector_type(4)));
typedef float    f4 __attribute__((ext_vector_type(4)));

// ---------- order-preserving float<->uint encode for atomicMax ----------
__device__ __forceinline__ unsigned encodeF(float f) {
    unsigned u = __float_as_uint(f);
    return (u & 0x80000000u) ? ~u : (u | 0x80000000u);
}
__device__ __forceinline__ float decodeF(unsigned u) {
    return (u & 0x80000000u) ? __uint_as_float(u & 0x7FFFFFFFu) : __uint_as_float(~u);
}

// ---------- fp32 -> fp16 convert with row padding ----------
__global__ __launch_bounds__(256)
void fp16_pad_convert(const float* __restrict__ in, _Float16* __restrict__ out,
                      int rows_in, int rows_out, int cols)
{
    size_t i4 = (size_t)blockIdx.x * 256 + threadIdx.x;
    size_t tot = ((size_t)rows_out * cols) >> 2;
    if (i4 >= tot) return;
    size_t e = i4 << 2;
    int row = (int)(e / cols);
    float vx = 0.f, vy = 0.f, vz = 0.f, vw = 0.f;
    if (row < rows_in) {
        float4 v = *(const float4*)(in + e);
        vx = v.x; vy = v.y; vz = v.z; vw = v.w;
    }
    h4v o = { (_Float16)vx, (_Float16)vy, (_Float16)vz, (_Float16)vw };
    *(h4v*)(out + e) = o;
}

// ---------- W[K][Ncols] fp32 -> Wt[rowOff+n][K] fp16 (zero for n >= Ncols) ----------
__global__ __launch_bounds__(256)
void transpose_to_fp16(const float* __restrict__ W, _Float16* __restrict__ Wt,
                       int K, int Ncols, int rowOff)
{
    __shared__ float tile[32][33];
    int n0 = blockIdx.x * 32, k0 = blockIdx.y * 32;
    int tx = threadIdx.x, ty = threadIdx.y;   // block (32,8)
    #pragma unroll
    for (int i = 0; i < 4; ++i) {
        int k = k0 + ty + i * 8;
        int n = n0 + tx;
        tile[ty + i * 8][tx] = (n < Ncols) ? W[(size_t)k * Ncols + n] : 0.f;
    }
    __syncthreads();
    #pragma unroll
    for (int i = 0; i < 4; ++i) {
        int n = n0 + ty + i * 8;
        int k = k0 + tx;
        Wt[(size_t)(rowOff + n) * K + k] = (_Float16)tile[tx][ty + i * 8];
    }
}

// ---------- pack biases: b1[6144] = bl||br ; b2[512] = bf padded 0 ----------
__global__ __launch_bounds__(256)
void bias_pack(const float* __restrict__ bl, const float* __restrict__ br,
               const float* __restrict__ bf, float* __restrict__ b1, float* __restrict__ b2)
{
    int i = blockIdx.x * 256 + threadIdx.x;
    if (i < HC) { b1[i] = bl[i]; b1[HC + i] = br[i]; }
    if (i < NCLS_P) b2[i] = (i < NCLS) ? bf[i] : 0.f;
}

// ---------- CSR build: histogram ----------
__global__ __launch_bounds__(256)
void csr_count(const int* __restrict__ ei, int* __restrict__ cnt)
{
    int e = blockIdx.x * 256 + threadIdx.x;
    if (e >= ETOT) return;
    int dst = (e < NEDGES) ? ei[2 * e + 1] : (e - NEDGES);
    atomicAdd(&cnt[dst], 1);
}

// ---------- CSR build: exclusive scan over 8000 counts (single block) ----------
__global__ __launch_bounds__(1024)
void csr_scan(const int* __restrict__ cnt, int* __restrict__ rofs)
{
    __shared__ int s[1024];
    int t = threadIdx.x;
    int base = t * 8;
    int local[8];
    int sum = 0;
    #pragma unroll
    for (int i = 0; i < 8; ++i) {
        local[i] = sum;
        sum += (base + i < NNODES) ? cnt[base + i] : 0;
    }
    s[t] = sum;
    __syncthreads();
    for (int off = 1; off < 1024; off <<= 1) {
        int v = (t >= off) ? s[t - off] : 0;
        __syncthreads();
        if (t >= off) s[t] += v;
        __syncthreads();
    }
    int pre = (t > 0) ? s[t - 1] : 0;
    #pragma unroll
    for (int i = 0; i < 8; ++i)
        if (base + i < NNODES) rofs[base + i] = pre + local[i];
}

// ---------- CSR build: fill edge lists ----------
__global__ __launch_bounds__(256)
void csr_fill(const int* __restrict__ ei, const int* __restrict__ rofs,
              int* __restrict__ cursor, int* __restrict__ csr_src, int* __restrict__ csr_e)
{
    int e = blockIdx.x * 256 + threadIdx.x;
    if (e >= ETOT) return;
    int src, dst;
    if (e < NEDGES) { src = ei[2 * e]; dst = ei[2 * e + 1]; }
    else            { src = dst = e - NEDGES; }
    int pos = rofs[dst] + atomicAdd(&cursor[dst], 1);
    csr_src[pos] = src;
    csr_e[pos]   = e;
}

// ---------- fp16 MFMA GEMM: C[Mpad][N] = A[Mpad][K] * Bt[N][K]^T + biasN ----------
__global__ __launch_bounds__(256, 3)
void gemm_f16(const _Float16* __restrict__ A, const _Float16* __restrict__ Bt,
              const float* __restrict__ biasN,
              float* __restrict__ C32, _Float16* __restrict__ C16,
              int N, int K)
{
    __shared__ __align__(16) _Float16 sA[128 * 32];
    __shared__ __align__(16) _Float16 sB[128 * 32];

    int nwg = gridDim.x;
    int orig = blockIdx.x;
    int q = nwg >> 3, r = nwg & 7;
    int xcd = orig & 7, idx = orig >> 3;
    int wg = (xcd < r ? xcd * (q + 1) : r * (q + 1) + (xcd - r) * q) + idx;
    int nbx = N >> 7;
    int bm = wg / nbx, bn = wg - bm * nbx;
    int m0 = bm << 7, n0 = bn << 7;

    const int t = threadIdx.x;
    const int lane = t & 63, w = t >> 6;
    const int wr = (w >> 1) << 6, wc = (w & 1) << 6;

    f4 acc[4][4];
    f4 zero = { 0.f, 0.f, 0.f, 0.f };
    #pragma unroll
    for (int i = 0; i < 4; ++i)
        #pragma unroll
        for (int j = 0; j < 4; ++j) acc[i][j] = zero;

    const int r0 = t >> 2, ks0 = t & 3;
    const int r1 = r0 + 64;
    const int wA0 = r0 * 32 + ((ks0 ^ ((r0 >> 1) & 3)) << 3);
    const int wA1 = r1 * 32 + ((ks0 ^ ((r1 >> 1) & 3)) << 3);
    const _Float16* gA0 = A  + (size_t)(m0 + r0) * K + ks0 * 8;
    const _Float16* gA1 = A  + (size_t)(m0 + r1) * K + ks0 * 8;
    const _Float16* gB0 = Bt + (size_t)(n0 + r0) * K + ks0 * 8;
    const _Float16* gB1 = Bt + (size_t)(n0 + r1) * K + ks0 * 8;

    uint4 stA0 = *(const uint4*)gA0;
    uint4 stA1 = *(const uint4*)gA1;
    uint4 stB0 = *(const uint4*)gB0;
    uint4 stB1 = *(const uint4*)gB1;

    const int nk = K >> 5;
    for (int s = 0; s < nk; ++s) {
        __syncthreads();
        *(uint4*)&sA[wA0] = stA0;
        *(uint4*)&sA[wA1] = stA1;
        *(uint4*)&sB[wA0] = stB0;
        *(uint4*)&sB[wA1] = stB1;
        __syncthreads();
        if (s + 1 < nk) {
            int koff = (s + 1) << 5;
            stA0 = *(const uint4*)(gA0 + koff);
            stA1 = *(const uint4*)(gA1 + koff);
            stB0 = *(const uint4*)(gB0 + koff);
            stB1 = *(const uint4*)(gB1 + koff);
        }
        const int ks = lane >> 4;
        h8 bh[4];
        #pragma unroll
        for (int nj = 0; nj < 4; ++nj) {
            int rn = wc + nj * 16 + (lane & 15);
            bh[nj] = *(const h8*)&sB[rn * 32 + ((ks ^ ((rn >> 1) & 3)) << 3)];
        }
        #pragma unroll
        for (int mi = 0; mi < 4; ++mi) {
            int rm = wr + mi * 16 + (lane & 15);
            h8 ah = *(const h8*)&sA[rm * 32 + ((ks ^ ((rm >> 1) & 3)) << 3)];
            #pragma unroll
            for (int nj = 0; nj < 4; ++nj)
                acc[mi][nj] = __builtin_amdgcn_mfma_f32_16x16x32_f16(ah, bh[nj], acc[mi][nj], 0, 0, 0);
        }
    }

    #pragma unroll
    for (int mi = 0; mi < 4; ++mi) {
        #pragma unroll
        for (int nj = 0; nj < 4; ++nj) {
            int col  = n0 + wc + nj * 16 + (lane & 15);
            int rowb = m0 + wr + mi * 16 + ((lane >> 4) << 2);
            float b = biasN[col];
            #pragma unroll
            for (int rg = 0; rg < 4; ++rg) {
                float v = acc[mi][nj][rg] + b;
                size_t off = (size_t)(rowb + rg) * N + col;
                if (C32) C32[off] = v;
                else     C16[off] = (_Float16)v;
            }
        }
    }
}

// ---------- scores: one wave per (edge, head) ----------
__global__ __launch_bounds__(256)
void edge_scores(const _Float16* __restrict__ xlr, const int* __restrict__ ei,
                 const float* __restrict__ att, float* __restrict__ sc,
                 unsigned* __restrict__ mEnc)
{
    int gw = (blockIdx.x << 2) + (threadIdx.x >> 6);
    if (gw >= ETOT * NH) return;
    int e = gw / 3, h = gw - e * 3;
    int lane = threadIdx.x & 63;
    int src, dst;
    if (e < NEDGES) { src = ei[2 * e]; dst = ei[2 * e + 1]; }
    else            { src = dst = e - NEDGES; }
    const _Float16* pl = xlr + (size_t)src * NTOT + h * CH + lane * 16;
    const _Float16* pr = xlr + (size_t)dst * NTOT + HC + h * CH + lane * 16;
    const float*    pa = att + h * CH + lane * 16;
    float s = 0.f;
    #pragma unroll
    for (int j = 0; j < 16; j += 8) {
        h8 vl = *(const h8*)(pl + j);
        h8 vr = *(const h8*)(pr + j);
        float4 a0 = *(const float4*)(pa + j);
        float4 a1 = *(const float4*)(pa + j + 4);
        float av[8] = { a0.x, a0.y, a0.z, a0.w, a1.x, a1.y, a1.z, a1.w };
        #pragma unroll
        for (int k = 0; k < 8; ++k) {
            float z = (float)vl[k] + (float)vr[k];
            z = z > 0.f ? z : NEG * z;
            s = fmaf(av[k], z, s);
        }
    }
    #pragma unroll
    for (int off = 32; off > 0; off >>= 1) s += __shfl_down(s, off);
    if (lane == 0) {
        sc[gw] = s;
        atomicMax(&mEnc[dst * NH + h], encodeF(s));
    }
}

// ---------- a = exp(e - m[dst]); denom[dst] += a ----------
__global__ __launch_bounds__(256)
void edge_exp(const int* __restrict__ ei, const unsigned* __restrict__ mEnc,
              float* __restrict__ sc, float* __restrict__ den)
{
    int g = blockIdx.x * 256 + threadIdx.x;
    if (g >= ETOT * NH) return;
    int e = g / 3, h = g - e * 3;
    int dst = (e < NEDGES) ? ei[2 * e + 1] : (e - NEDGES);
    float m = decodeF(mEnc[dst * NH + h]);
    float a = expf(sc[g] - m);
    sc[g] = a;
    atomicAdd(&den[dst * NH + h], a);
}

// ---------- CSR gather: o2h[dst] = fp16( bias + sum_e sum_h alpha/3 * xl[src,h,:] ) ----------
__global__ __launch_bounds__(256)
void gather_out(const _Float16* __restrict__ xlr, const int* __restrict__ rofs,
                const int* __restrict__ cnt, const int* __restrict__ csr_src,
                const int* __restrict__ csr_e, const float* __restrict__ sc,
                const float* __restrict__ den, const float* __restrict__ bias,
                _Float16* __restrict__ o2h)
{
    const int dst = blockIdx.x;
    const int t = threadIdx.x;
    if (dst >= NNODES) {           // pad rows for GEMM2
        h4v z = { (_Float16)0.f, (_Float16)0.f, (_Float16)0.f, (_Float16)0.f };
        *(h4v*)(o2h + (size_t)dst * CH + 4 * t) = z;
        return;
    }
    const int beg = rofs[dst];
    const int num = cnt[dst];
    const float d0 = 1.f / (den[dst * 3 + 0] + 1e-16f) * (1.f / 3.f);
    const float d1 = 1.f / (den[dst * 3 + 1] + 1e-16f) * (1.f / 3.f);
    const float d2 = 1.f / (den[dst * 3 + 2] + 1e-16f) * (1.f / 3.f);
    float a0 = 0.f, a1 = 0.f, a2 = 0.f, a3 = 0.f;
    for (int i = 0; i < num; ++i) {
        int src = csr_src[beg + i];
        int e   = csr_e[beg + i];
        float c0 = sc[e * 3 + 0] * d0;
        float c1 = sc[e * 3 + 1] * d1;
        float c2 = sc[e * 3 + 2] * d2;
        const _Float16* p = xlr + (size_t)src * NTOT + 4 * t;
        h4v v0 = *(const h4v*)(p);
        h4v v1 = *(const h4v*)(p + CH);
        h4v v2 = *(const h4v*)(p + 2 * CH);
        a0 += c0 * (float)v0[0] + c1 * (float)v1[0] + c2 * (float)v2[0];
        a1 += c0 * (float)v0[1] + c1 * (float)v1[1] + c2 * (float)v2[1];
        a2 += c0 * (float)v0[2] + c1 * (float)v1[2] + c2 * (float)v2[2];
        a3 += c0 * (float)v0[3] + c1 * (float)v1[3] + c2 * (float)v2[3];
    }
    const float4 b = *(const float4*)(bias + 4 * t);
    h4v o = { (_Float16)(a0 + b.x), (_Float16)(a1 + b.y),
              (_Float16)(a2 + b.z), (_Float16)(a3 + b.w) };
    *(h4v*)(o2h + (size_t)dst * CH + 4 * t) = o;
}

// ---------- row softmax over 460 classes, ld 512 ----------
__global__ __launch_bounds__(64)
void row_softmax(const float* __restrict__ logits, float* __restrict__ out)
{
    const int r = blockIdx.x;
    const int lane = threadIdx.x;
    const float* row = logits + (size_t)r * NCLS_P;
    float v[8];
    float mx = -3.4e38f;
    #pragma unroll
    for (int i = 0; i < 8; ++i) {
        int c = lane + i * 64;
        v[i] = (c < NCLS) ? row[c] : -3.4e38f;
        mx = fmaxf(mx, v[i]);
    }
    #pragma unroll
    for (int off = 32; off > 0; off >>= 1) mx = fmaxf(mx, __shfl_xor(mx, off));
    float s = 0.f;
    #pragma unroll
    for (int i = 0; i < 8; ++i) {
        int c = lane + i * 64;
        float ev = (c < NCLS) ? expf(v[i] - mx) : 0.f;
        v[i] = ev;
        s += ev;
    }
    #pragma unroll
    for (int off = 32; off > 0; off >>= 1) s += __shfl_xor(s, off);
    float inv = 1.f / s;
    #pragma unroll
    for (int i = 0; i < 8; ++i) {
        int c = lane + i * 64;
        if (c < NCLS) out[(size_t)r * NCLS + c] = v[i] * inv;
    }
}

extern "C" void kernel_launch(void* const* d_in, const int* in_sizes, int n_in,
                              void* d_out, int out_size, void* d_ws, size_t ws_size,
                              hipStream_t stream)
{
    (void)in_sizes; (void)n_in; (void)out_size; (void)ws_size;

    const float* x    = (const float*)d_in[0];
    const int*   ei   = (const int*)  d_in[1];
    const float* Wl   = (const float*)d_in[2];
    const float* bl   = (const float*)d_in[3];
    const float* Wr   = (const float*)d_in[4];
    const float* br   = (const float*)d_in[5];
    const float* att  = (const float*)d_in[6];
    const float* bias = (const float*)d_in[7];
    const float* Wf   = (const float*)d_in[8];
    const float* bf   = (const float*)d_in[9];

    char* base = (char*)d_ws;
    _Float16* xh      = (_Float16*)(base);                      // [8064][1024]
    _Float16* BtW     = (_Float16*)(base + 16515072);           // [6144][1024]
    _Float16* Wft     = (_Float16*)(base + 29097984);           // [512][1024]
    float*    biasC1  = (float*)   (base + 30146560);           // [6144]
    float*    biasC2  = (float*)   (base + 30171136);           // [512]
    float*    sc      = (float*)   (base + 30173184);           // [48000*3]
    unsigned* mEnc    = (unsigned*)(base + 30749184);           // [24000]
    float*    den     = (float*)   (base + 30845184);           // [24000]
    int*      cnt     = (int*)     (base + 30941184);           // [8000]
    int*      cursor  = (int*)     (base + 30973184);           // [8000]
    int*      rofs    = (int*)     (base + 31005184);           // [8000]
    int*      csr_src = (int*)     (base + 31037184);           // [48000]
    int*      csr_e   = (int*)     (base + 31229184);           // [48000]
    _Float16* o2h     = (_Float16*)(base + 31421184);           // [8064][1024]
    float*    logits  = (float*)   (base + 47936256);           // [8064][512]
    _Float16* xlr     = (_Float16*)(base + 64451328);           // [8064][6144]

    // zero mEnc | den | cnt | cursor (contiguous, 256 KB)
    hipMemsetAsync(mEnc, 0, 256000, stream);

    fp16_pad_convert<<<(MPAD * DIN / 4 + 255) / 256, 256, 0, stream>>>(
        x, xh, NNODES, MPAD, DIN);

    transpose_to_fp16<<<dim3(HC / 32, DIN / 32), dim3(32, 8), 0, stream>>>(Wl, BtW, DIN, HC, 0);
    transpose_to_fp16<<<dim3(HC / 32, DIN / 32), dim3(32, 8), 0, stream>>>(Wr, BtW, DIN, HC, HC);
    transpose_to_fp16<<<dim3(NCLS_P / 32, DIN / 32), dim3(32, 8), 0, stream>>>(Wf, Wft, DIN, NCLS, 0);

    bias_pack<<<(HC + 255) / 256, 256, 0, stream>>>(bl, br, bf, biasC1, biasC2);

    // CSR build
    csr_count<<<(ETOT + 255) / 256, 256, 0, stream>>>(ei, cnt);
    csr_scan<<<1, 1024, 0, stream>>>(cnt, rofs);
    csr_fill<<<(ETOT + 255) / 256, 256, 0, stream>>>(ei, rofs, cursor, csr_src, csr_e);

    // GEMM1 fused: xlr[8064][6144] fp16
    gemm_f16<<<(NTOT / 128) * (MPAD / 128), 256, 0, stream>>>(
        xh, BtW, biasC1, nullptr, xlr, NTOT, DIN);

    // edge path
    edge_scores<<<(ETOT * NH + 3) / 4, 256, 0, stream>>>(xlr, ei, att, sc, mEnc);
    edge_exp<<<(ETOT * NH + 255) / 256, 256, 0, stream>>>(ei, mEnc, sc, den);

    // CSR gather (+bias, fp16, pads rows 8000..8063)
    gather_out<<<MPAD, 256, 0, stream>>>(xlr, rofs, cnt, csr_src, csr_e, sc, den, bias, o2h);

    // GEMM2: logits[8064][512] fp32
    gemm_f16<<<(NCLS_P / 128) * (MPAD / 128), 256, 0, stream>>>(
        o2h, Wft, biasC2, logits, nullptr, NCLS_P, DIN);

    row_softmax<<<NNODES, 64, 0, stream>>>(logits, (float*)d_out);
}

// Round 6
// 399.389 us; speedup vs baseline: 6.2578x; 1.1154x over previous
//
#include <hip/hip_runtime.h>

#define NNODES 8000
#define MPAD   8064          // 63 * 128
#define NEDGES 40000
#define ETOT   (NEDGES + NNODES)   // 48000 with self loops
#define DIN    1024
#define NH     3
#define CH     1024
#define HC     (NH * CH)           // 3072
#define NTOT   (2 * HC)            // 6144 fused xl||xr
#define NCLS   460
#define NCLS_P 512
#define NEG    0.2f

typedef _Float16 h8 __attribute__((ext_vector_type(8)));
typedef _Float16 h4v __attribute__((ext_vector_type(4)));
typedef float    f4 __attribute__((ext_vector_type(4)));

// ---------- fp32 -> fp16 convert with row padding ----------
__global__ __launch_bounds__(256)
void fp16_pad_convert(const float* __restrict__ in, _Float16* __restrict__ out,
                      int rows_in, int rows_out, int cols)
{
    size_t i4 = (size_t)blockIdx.x * 256 + threadIdx.x;
    size_t tot = ((size_t)rows_out * cols) >> 2;
    if (i4 >= tot) return;
    size_t e = i4 << 2;
    int row = (int)(e / cols);
    float vx = 0.f, vy = 0.f, vz = 0.f, vw = 0.f;
    if (row < rows_in) {
        float4 v = *(const float4*)(in + e);
        vx = v.x; vy = v.y; vz = v.z; vw = v.w;
    }
    h4v o = { (_Float16)vx, (_Float16)vy, (_Float16)vz, (_Float16)vw };
    *(h4v*)(out + e) = o;
}

// ---------- W[K][Ncols] fp32 -> Wt[rowOff+n][K] fp16 (zero for n >= Ncols) ----------
__global__ __launch_bounds__(256)
void transpose_to_fp16(const float* __restrict__ W, _Float16* __restrict__ Wt,
                       int K, int Ncols, int rowOff)
{
    __shared__ float tile[32][33];
    int n0 = blockIdx.x * 32, k0 = blockIdx.y * 32;
    int tx = threadIdx.x, ty = threadIdx.y;   // block (32,8)
    #pragma unroll
    for (int i = 0; i < 4; ++i) {
        int k = k0 + ty + i * 8;
        int n = n0 + tx;
        tile[ty + i * 8][tx] = (n < Ncols) ? W[(size_t)k * Ncols + n] : 0.f;
    }
    __syncthreads();
    #pragma unroll
    for (int i = 0; i < 4; ++i) {
        int n = n0 + ty + i * 8;
        int k = k0 + tx;
        Wt[(size_t)(rowOff + n) * K + k] = (_Float16)tile[tx][ty + i * 8];
    }
}

// ---------- pack biases: b1[6144] = bl||br ; b2[512] = bf padded 0 ----------
__global__ __launch_bounds__(256)
void bias_pack(const float* __restrict__ bl, const float* __restrict__ br,
               const float* __restrict__ bf, float* __restrict__ b1, float* __restrict__ b2)
{
    int i = blockIdx.x * 256 + threadIdx.x;
    if (i < HC) { b1[i] = bl[i]; b1[HC + i] = br[i]; }
    if (i < NCLS_P) b2[i] = (i < NCLS) ? bf[i] : 0.f;
}

// ---------- CSR build: histogram ----------
__global__ __launch_bounds__(256)
void csr_count(const int* __restrict__ ei, int* __restrict__ cnt)
{
    int e = blockIdx.x * 256 + threadIdx.x;
    if (e >= ETOT) return;
    int dst = (e < NEDGES) ? ei[2 * e + 1] : (e - NEDGES);
    atomicAdd(&cnt[dst], 1);
}

// ---------- CSR build: exclusive scan over 8000 counts (single block) ----------
__global__ __launch_bounds__(1024)
void csr_scan(const int* __restrict__ cnt, int* __restrict__ rofs)
{
    __shared__ int s[1024];
    int t = threadIdx.x;
    int base = t * 8;
    int local[8];
    int sum = 0;
    #pragma unroll
    for (int i = 0; i < 8; ++i) {
        local[i] = sum;
        sum += (base + i < NNODES) ? cnt[base + i] : 0;
    }
    s[t] = sum;
    __syncthreads();
    for (int off = 1; off < 1024; off <<= 1) {
        int v = (t >= off) ? s[t - off] : 0;
        __syncthreads();
        if (t >= off) s[t] += v;
        __syncthreads();
    }
    int pre = (t > 0) ? s[t - 1] : 0;
    #pragma unroll
    for (int i = 0; i < 8; ++i)
        if (base + i < NNODES) rofs[base + i] = pre + local[i];
}

// ---------- CSR build: fill src lists ----------
__global__ __launch_bounds__(256)
void csr_fill(const int* __restrict__ ei, const int* __restrict__ rofs,
              int* __restrict__ cursor, int* __restrict__ csr_src)
{
    int e = blockIdx.x * 256 + threadIdx.x;
    if (e >= ETOT) return;
    int src, dst;
    if (e < NEDGES) { src = ei[2 * e]; dst = ei[2 * e + 1]; }
    else            { src = dst = e - NEDGES; }
    int pos = rofs[dst] + atomicAdd(&cursor[dst], 1);
    csr_src[pos] = src;
}

// ---------- fp16 MFMA GEMM: C[Mpad][N] = A[Mpad][K] * Bt[N][K]^T + biasN ----------
__global__ __launch_bounds__(256, 3)
void gemm_f16(const _Float16* __restrict__ A, const _Float16* __restrict__ Bt,
              const float* __restrict__ biasN,
              float* __restrict__ C32, _Float16* __restrict__ C16,
              int N, int K)
{
    __shared__ __align__(16) _Float16 sA[128 * 32];
    __shared__ __align__(16) _Float16 sB[128 * 32];

    int nwg = gridDim.x;
    int orig = blockIdx.x;
    int q = nwg >> 3, r = nwg & 7;
    int xcd = orig & 7, idx = orig >> 3;
    int wg = (xcd < r ? xcd * (q + 1) : r * (q + 1) + (xcd - r) * q) + idx;
    int nbx = N >> 7;
    int bm = wg / nbx, bn = wg - bm * nbx;
    int m0 = bm << 7, n0 = bn << 7;

    const int t = threadIdx.x;
    const int lane = t & 63, w = t >> 6;
    const int wr = (w >> 1) << 6, wc = (w & 1) << 6;

    f4 acc[4][4];
    f4 zero = { 0.f, 0.f, 0.f, 0.f };
    #pragma unroll
    for (int i = 0; i < 4; ++i)
        #pragma unroll
        for (int j = 0; j < 4; ++j) acc[i][j] = zero;

    const int r0 = t >> 2, ks0 = t & 3;
    const int r1 = r0 + 64;
    const int wA0 = r0 * 32 + ((ks0 ^ ((r0 >> 1) & 3)) << 3);
    const int wA1 = r1 * 32 + ((ks0 ^ ((r1 >> 1) & 3)) << 3);
    const _Float16* gA0 = A  + (size_t)(m0 + r0) * K + ks0 * 8;
    const _Float16* gA1 = A  + (size_t)(m0 + r1) * K + ks0 * 8;
    const _Float16* gB0 = Bt + (size_t)(n0 + r0) * K + ks0 * 8;
    const _Float16* gB1 = Bt + (size_t)(n0 + r1) * K + ks0 * 8;

    uint4 stA0 = *(const uint4*)gA0;
    uint4 stA1 = *(const uint4*)gA1;
    uint4 stB0 = *(const uint4*)gB0;
    uint4 stB1 = *(const uint4*)gB1;

    const int nk = K >> 5;
    for (int s = 0; s < nk; ++s) {
        __syncthreads();
        *(uint4*)&sA[wA0] = stA0;
        *(uint4*)&sA[wA1] = stA1;
        *(uint4*)&sB[wA0] = stB0;
        *(uint4*)&sB[wA1] = stB1;
        __syncthreads();
        if (s + 1 < nk) {
            int koff = (s + 1) << 5;
            stA0 = *(const uint4*)(gA0 + koff);
            stA1 = *(const uint4*)(gA1 + koff);
            stB0 = *(const uint4*)(gB0 + koff);
            stB1 = *(const uint4*)(gB1 + koff);
        }
        const int ks = lane >> 4;
        h8 bh[4];
        #pragma unroll
        for (int nj = 0; nj < 4; ++nj) {
            int rn = wc + nj * 16 + (lane & 15);
            bh[nj] = *(const h8*)&sB[rn * 32 + ((ks ^ ((rn >> 1) & 3)) << 3)];
        }
        #pragma unroll
        for (int mi = 0; mi < 4; ++mi) {
            int rm = wr + mi * 16 + (lane & 15);
            h8 ah = *(const h8*)&sA[rm * 32 + ((ks ^ ((rm >> 1) & 3)) << 3)];
            #pragma unroll
            for (int nj = 0; nj < 4; ++nj)
                acc[mi][nj] = __builtin_amdgcn_mfma_f32_16x16x32_f16(ah, bh[nj], acc[mi][nj], 0, 0, 0);
        }
    }

    #pragma unroll
    for (int mi = 0; mi < 4; ++mi) {
        #pragma unroll
        for (int nj = 0; nj < 4; ++nj) {
            int col  = n0 + wc + nj * 16 + (lane & 15);
            int rowb = m0 + wr + mi * 16 + ((lane >> 4) << 2);
            float b = biasN[col];
            #pragma unroll
            for (int rg = 0; rg < 4; ++rg) {
                float v = acc[mi][nj][rg] + b;
                size_t off = (size_t)(rowb + rg) * N + col;
                if (C32) C32[off] = v;
                else     C16[off] = (_Float16)v;
            }
        }
    }
}

// ---------- fused edge path: one block per dst, flash-style online softmax ----------
// 384 threads: thread t -> head h = t>>7, channels c0 = (t&127)*8 .. +8.
// Per in-edge: read xl[src] once; score via lrelu+att dot (wave reduce);
// online update of (m, denom, acc[8]) per head. Final head-sum via LDS.
__global__ __launch_bounds__(384)
void edge_fused(const _Float16* __restrict__ xlr, const int* __restrict__ rofs,
                const int* __restrict__ cnt, const int* __restrict__ csr_src,
                const float* __restrict__ att, const float* __restrict__ bias,
                _Float16* __restrict__ o2h)
{
    __shared__ float red[6];
    __shared__ float outs[HC];

    const int dst = blockIdx.x;
    const int t   = threadIdx.x;
    const int h   = t >> 7;
    const int c0  = (t & 127) << 3;
    const int wid = t >> 6;

    // xr[dst] slice and att slice -> registers (fp32)
    h8 xrv = *(const h8*)(xlr + (size_t)dst * NTOT + HC + h * CH + c0);
    float xrf[8], atf[8];
    {
        float4 a0 = *(const float4*)(att + h * CH + c0);
        float4 a1 = *(const float4*)(att + h * CH + c0 + 4);
        atf[0] = a0.x; atf[1] = a0.y; atf[2] = a0.z; atf[3] = a0.w;
        atf[4] = a1.x; atf[5] = a1.y; atf[6] = a1.z; atf[7] = a1.w;
        #pragma unroll
        for (int j = 0; j < 8; ++j) xrf[j] = (float)xrv[j];
    }

    const int beg = rofs[dst];
    const int num = cnt[dst];

    float m = -3.4e38f, d = 0.f;
    float acc[8];
    #pragma unroll
    for (int j = 0; j < 8; ++j) acc[j] = 0.f;

    for (int i = 0; i < num; ++i) {
        int src = csr_src[beg + i];
        h8 xv = *(const h8*)(xlr + (size_t)src * NTOT + h * CH + c0);
        float s = 0.f;
        #pragma unroll
        for (int j = 0; j < 8; ++j) {
            float z = (float)xv[j] + xrf[j];
            z = z > 0.f ? z : NEG * z;
            s = fmaf(atf[j], z, s);
        }
        #pragma unroll
        for (int off = 32; off > 0; off >>= 1) s += __shfl_down(s, off);
        if ((t & 63) == 0) red[wid] = s;
        __syncthreads();
        float e = red[h << 1] + red[(h << 1) + 1];
        float nm = fmaxf(m, e);
        float sc_ = __expf(m - nm);   // first iter: exp(-big)=0
        float w   = __expf(e - nm);
        d = d * sc_ + w;
        #pragma unroll
        for (int j = 0; j < 8; ++j) acc[j] = fmaf(w, (float)xv[j], acc[j] * sc_);
        m = nm;
        __syncthreads();
    }

    float inv = 1.f / (d + 1e-16f) * (1.f / 3.f);
    #pragma unroll
    for (int j = 0; j < 8; ++j) outs[h * CH + c0 + j] = acc[j] * inv;
    __syncthreads();

    if (t < 256) {
        int c = t << 2;
        float4 b = *(const float4*)(bias + c);
        float v0 = outs[c + 0] + outs[CH + c + 0] + outs[2 * CH + c + 0] + b.x;
        float v1 = outs[c + 1] + outs[CH + c + 1] + outs[2 * CH + c + 1] + b.y;
        float v2 = outs[c + 2] + outs[CH + c + 2] + outs[2 * CH + c + 2] + b.z;
        float v3 = outs[c + 3] + outs[CH + c + 3] + outs[2 * CH + c + 3] + b.w;
        h4v o = { (_Float16)v0, (_Float16)v1, (_Float16)v2, (_Float16)v3 };
        *(h4v*)(o2h + (size_t)dst * CH + c) = o;
    }
}

// ---------- row softmax over 460 classes, ld 512 ----------
__global__ __launch_bounds__(64)
void row_softmax(const float* __restrict__ logits, float* __restrict__ out)
{
    const int r = blockIdx.x;
    const int lane = threadIdx.x;
    const float* row = logits + (size_t)r * NCLS_P;
    float v[8];
    float mx = -3.4e38f;
    #pragma unroll
    for (int i = 0; i < 8; ++i) {
        int c = lane + i * 64;
        v[i] = (c < NCLS) ? row[c] : -3.4e38f;
        mx = fmaxf(mx, v[i]);
    }
    #pragma unroll
    for (int off = 32; off > 0; off >>= 1) mx = fmaxf(mx, __shfl_xor(mx, off));
    float s = 0.f;
    #pragma unroll
    for (int i = 0; i < 8; ++i) {
        int c = lane + i * 64;
        float ev = (c < NCLS) ? expf(v[i] - mx) : 0.f;
        v[i] = ev;
        s += ev;
    }
    #pragma unroll
    for (int off = 32; off > 0; off >>= 1) s += __shfl_xor(s, off);
    float inv = 1.f / s;
    #pragma unroll
    for (int i = 0; i < 8; ++i) {
        int c = lane + i * 64;
        if (c < NCLS) out[(size_t)r * NCLS + c] = v[i] * inv;
    }
}

extern "C" void kernel_launch(void* const* d_in, const int* in_sizes, int n_in,
                              void* d_out, int out_size, void* d_ws, size_t ws_size,
                              hipStream_t stream)
{
    (void)in_sizes; (void)n_in; (void)out_size; (void)ws_size;

    const float* x    = (const float*)d_in[0];
    const int*   ei   = (const int*)  d_in[1];
    const float* Wl   = (const float*)d_in[2];
    const float* bl   = (const float*)d_in[3];
    const float* Wr   = (const float*)d_in[4];
    const float* br   = (const float*)d_in[5];
    const float* att  = (const float*)d_in[6];
    const float* bias = (const float*)d_in[7];
    const float* Wf   = (const float*)d_in[8];
    const float* bf   = (const float*)d_in[9];

    char* base = (char*)d_ws;
    _Float16* xh      = (_Float16*)(base);                      // [8064][1024]   16,515,072
    _Float16* BtW     = (_Float16*)(base + 16515072);           // [6144][1024]   12,582,912
    _Float16* Wft     = (_Float16*)(base + 29097984);           // [512][1024]     1,048,576
    float*    biasC1  = (float*)   (base + 30146560);           // [6144]             24,576
    float*    biasC2  = (float*)   (base + 30171136);           // [512]               2,048
    int*      cnt     = (int*)     (base + 30173184);           // [8000]             32,000
    int*      cursor  = (int*)     (base + 30205184);           // [8000]             32,000
    int*      rofs    = (int*)     (base + 30237184);           // [8000]             32,000
    int*      csr_src = (int*)     (base + 30269184);           // [48000]           192,000
    _Float16* o2h     = (_Float16*)(base + 30461184);           // [8064][1024]   16,515,072
    float*    logits  = (float*)   (base + 46976256);           // [8064][512]    16,515,072
    _Float16* xlr     = (_Float16*)(base + 63491328);           // [8064][6144]   99,090,432

    // zero cnt | cursor (contiguous, 64 KB) and o2h pad rows (rows 8000..8063)
    hipMemsetAsync(cnt, 0, 64000, stream);
    hipMemsetAsync(o2h + (size_t)NNODES * CH, 0, (size_t)(MPAD - NNODES) * CH * 2, stream);

    fp16_pad_convert<<<(MPAD * DIN / 4 + 255) / 256, 256, 0, stream>>>(
        x, xh, NNODES, MPAD, DIN);

    transpose_to_fp16<<<dim3(HC / 32, DIN / 32), dim3(32, 8), 0, stream>>>(Wl, BtW, DIN, HC, 0);
    transpose_to_fp16<<<dim3(HC / 32, DIN / 32), dim3(32, 8), 0, stream>>>(Wr, BtW, DIN, HC, HC);
    transpose_to_fp16<<<dim3(NCLS_P / 32, DIN / 32), dim3(32, 8), 0, stream>>>(Wf, Wft, DIN, NCLS, 0);

    bias_pack<<<(HC + 255) / 256, 256, 0, stream>>>(bl, br, bf, biasC1, biasC2);

    // CSR build (src lists per dst, self-loops included)
    csr_count<<<(ETOT + 255) / 256, 256, 0, stream>>>(ei, cnt);
    csr_scan<<<1, 1024, 0, stream>>>(cnt, rofs);
    csr_fill<<<(ETOT + 255) / 256, 256, 0, stream>>>(ei, rofs, cursor, csr_src);

    // GEMM1 fused: xlr[8064][6144] fp16
    gemm_f16<<<(NTOT / 128) * (MPAD / 128), 256, 0, stream>>>(
        xh, BtW, biasC1, nullptr, xlr, NTOT, DIN);

    // fused edge path: scores + online softmax + weighted gather + bias, fp16 out
    edge_fused<<<NNODES, 384, 0, stream>>>(xlr, rofs, cnt, csr_src, att, bias, o2h);

    // GEMM2: logits[8064][512] fp32
    gemm_f16<<<(NCLS_P / 128) * (MPAD / 128), 256, 0, stream>>>(
        o2h, Wft, biasC2, logits, nullptr, NCLS_P, DIN);

    row_softmax<<<NNODES, 64, 0, stream>>>(logits, (float*)d_out);
}